// Round 15
// baseline (70.551 us; speedup 1.0000x reference)
//
#include <hip/hip_runtime.h>

#define NIN 784
#define WIDTH 1024
#define HALF 512
#define DEPTH 8
#define BDEPTH 10
#define BATCH 4096
#define SPLINE_DIM 20
#define NQ 18   // knot intervals [t_m, t_m+1), m = 2..19

// Clamped knot vector T[23]: [-8]*3, +-2^k/32 ladder, 0, [8]*3
__device__ float d_T[23] = {
  -8.f, -8.f, -8.f, -4.f, -2.f, -1.f, -0.5f, -0.25f, -0.125f, -0.0625f,
  -0.03125f, 0.f, 0.03125f, 0.0625f, 0.125f, 0.25f, 0.5f, 1.f, 2.f, 4.f,
  8.f, 8.f, 8.f };

// ---------------------------------------------------------------------------
// Prep kernel (IDENTICAL to validated R14). cs layout per layer (10240 f2):
//   d in 0..3 : [d*1024 + slot] = (c_d, s_d)
//   pairs p=0..2 (d=4+2p, d+1): [4096 + p*2048 + slot*2 + {0,1}]
//   -> one ds_read_b128 per slot feeds two consecutive steps.
// qt quadratic spline unchanged (validated R3+).
// ---------------------------------------------------------------------------
__global__ void prep_kernel(const float* __restrict__ bp,
                            const float* __restrict__ sc,
                            float2* __restrict__ cs,
                            float4* __restrict__ qt) {
  int gid = blockIdx.x * 256 + threadIdx.x;
  if (gid < DEPTH * BDEPTH * 1024) {
    int slot = gid & 1023;
    int d = (gid >> 10) % BDEPTH;
    int i = gid / (BDEPTH * 1024);
    int n = 0;
#pragma unroll
    for (int b = 0; b < 10; ++b) {
      int src = b - d; if (src < 0) src += 10;
      n |= ((slot >> src) & 1) << b;
    }
    int pj = n & 511;
    float theta = bp[(i * HALF + pj) * BDEPTH + d];
    float c = cosf(theta), s = sinf(theta);
    float2 val = make_float2(c, (n & 512) ? -s : s);
    int off;
    if (d < 4) off = i * 10240 + d * 1024 + slot;
    else {
      int p = (d - 4) >> 1, sub = (d - 4) & 1;
      off = i * 10240 + 4096 + p * 2048 + slot * 2 + sub;
    }
    cs[off] = val;
  }
  int gid2 = gid - DEPTH * BDEPTH * 1024;
  if (gid2 >= 0 && gid2 < (DEPTH - 1) * NQ * HALF) {
    int w = gid2 & 511;
    int mi = (gid2 >> 9) % NQ;
    int i = gid2 / (NQ * HALF);
    int m = mi + 2;
    const float* cf = sc + (i * HALF + w) * SPLINE_DIM;
    double c0 = cf[mi], c1 = cf[mi + 1], c2 = cf[mi + 2];
    double tm1 = d_T[m - 1], tm = d_T[m], tp1 = d_T[m + 1], tp2 = d_T[m + 2];
    double h = tp1 - tm;
    double us[3] = { 0.0, 0.5 * h, 0.75 * h };
    double y[3];
#pragma unroll
    for (int k = 0; k < 3; ++k) {
      double x = tm + us[k];
      double left1 = x - tm, right1 = tp1 - x, left2 = x - tm1, right2 = tp2 - x;
      double inv1 = 1.0 / (tp1 - tm);
      double N0 = right1 * inv1, N1 = left1 * inv1;
      double temp0 = N0 / (tp1 - tm1);
      double B0 = right1 * temp0;
      double saved = left2 * temp0;
      double temp1 = N1 / (tp2 - tm);
      double B1 = right2 * temp1 + saved;
      double B2 = left1 * temp1;
      y[k] = c0 * B0 + c1 * B1 + c2 * B2;
    }
    double d1 = y[1] - y[0], d2 = y[2] - y[0];
    double u1 = us[1], u2 = us[2];
    double det = u1 * u2 * (u2 - u1);
    double Bq = (d1 * u2 * u2 - d2 * u1 * u1) / det;
    double Cq = (d2 * u1 - d1 * u2) / det;
    qt[gid2] = make_float4((float)y[0], (float)Bq, (float)Cq, (float)tm);
  }
}

// ---------------------------------------------------------------------------
// Compile-time lane shuffles (validated): DPP xor1/2, ds_swizzle 4/8/16,
// bpermute for 32.
// ---------------------------------------------------------------------------
template <int M>
__device__ __forceinline__ float shfx(float x) {
  if constexpr (M == 1)
    return __int_as_float(__builtin_amdgcn_mov_dpp(__float_as_int(x), 0xB1, 0xF, 0xF, true));
  else if constexpr (M == 2)
    return __int_as_float(__builtin_amdgcn_mov_dpp(__float_as_int(x), 0x4E, 0xF, 0xF, true));
  else if constexpr (M == 4)
    return __int_as_float(__builtin_amdgcn_ds_swizzle(__float_as_int(x), 0x101F));
  else if constexpr (M == 8)
    return __int_as_float(__builtin_amdgcn_ds_swizzle(__float_as_int(x), 0x201F));
  else if constexpr (M == 16)
    return __int_as_float(__builtin_amdgcn_ds_swizzle(__float_as_int(x), 0x401F));
  else
    return __shfl_xor(x, 32, 64);
}

// Quadratic spline activation (validated R3+).
__device__ __forceinline__ float qspline(float x, const float4* __restrict__ qL, int w) {
  x = fminf(fmaxf(x, -8.0f), 7.9999990f);
  float ax = fabsf(x);
  unsigned bits = __float_as_uint(ax);
  int e = (int)(bits >> 23) - 127;
  int ce = e + ((bits & 0x7fffffu) ? 1 : 0);
  int m = (x > 0.f) ? (17 + e) : (5 - ce);
  m = (ax < 0.03125f) ? ((x < 0.f) ? 10 : 11) : m;
  float4 qc = qL[(m - 2) * HALF + w];
  float u = x - qc.w;
  return fmaf(u, fmaf(u, qc.z, qc.y), qc.x);
}

typedef __attribute__((address_space(3))) unsigned int lds_u32;
typedef __attribute__((address_space(1))) const unsigned int glb_u32;

// Async-stage one full layer (80 KB) into LDS buffer `dst` via global_load_lds
// (16B/lane DMA). 80 wave-segments of 1 KB; wave wv (0..15) takes segs
// {k*16+wv}, k=0..4 -> 5 DMAs/wave; wait with counted vmcnt(5) one layer later.
__device__ __forceinline__ void stage_async(const float2* __restrict__ src,
                                            float2* dst, int wv) {
#pragma unroll
  for (int k = 0; k < 5; ++k) {
    int seg = k * 16 + wv;
    const char* g = (const char*)src + seg * 1024 + (threadIdx.x & 63) * 16;
    char* l = (char*)dst + seg * 1024;
    __builtin_amdgcn_global_load_lds((glb_u32*)g, (lds_u32*)l, 16, 0, 0);
  }
}

// butterfly step dd<4: partner = reg ^ (8>>dd), one row
#define CSTEPL(dd) do {                                                       \
    const int _mr = 8 >> (dd);                                                \
    _Pragma("unroll") for (int r = 0; r < 16; ++r)                            \
      if ((r & _mr) == 0) {                                                   \
        float2 v = cur[(dd) * 1024 + r * 64 + lane];                          \
        float a0 = s0[r], b0 = s0[r + _mr];                                   \
        s0[r]       = fmaf(a0, v.x, b0 * v.y);                                \
        s0[r + _mr] = fmaf(b0, v.x, -(a0 * v.y));                             \
      }                                                                       \
  } while (0)

// paired lane-steps: one b128 feeds steps (mask M1) then (mask M2)
#define LPAIR(p, M1, M2) do {                                                 \
    const float4* _pp = (const float4*)(cur + 4096 + (p) * 2048);             \
    _Pragma("unroll") for (int r = 0; r < 16; ++r) {                          \
      float4 v = _pp[r * 64 + lane];                                          \
      float q1 = shfx<M1>(s0[r]);                                             \
      s0[r] = fmaf(s0[r], v.x, q1 * v.y);                                     \
      float q2 = shfx<M2>(s0[r]);                                             \
      s0[r] = fmaf(s0[r], v.z, q2 * v.w);                                     \
    }                                                                         \
  } while (0)

// ---------------------------------------------------------------------------
// Main kernel: 256 blocks x 1024 threads (16 waves), ONE row per wave.
// Same full-layer 160 KB async double-buffer and 2-barriers/layer as R14,
// but 4 waves/SIMD (was 2): the in-phase LDS latency that R14's counters
// implicated now has 2x the wave-level overlap. Total staging traffic
// unchanged (16 rows share each block's table).
// ---------------------------------------------------------------------------
__global__ __launch_bounds__(1024, 1) void fwd_kernel(
    const float* __restrict__ X, const float2* __restrict__ cs,
    const float4* __restrict__ qt, float* __restrict__ out) {
  __shared__ float2 bufA[10240];   // 80 KB
  __shared__ float2 bufB[10240];   // 80 KB
  int tid = threadIdx.x;
  int lane = tid & 63;
  int wv = tid >> 6;                       // 0..15
  int row = blockIdx.x * 16 + wv;

  const float* xp = X + (long)row * NIN;
  float s0[16];
#pragma unroll
  for (int r = 0; r < 16; ++r) {
    int w = r * 64 + lane;
    s0[r] = (w < NIN) ? xp[w] : 0.f;
  }

  // prologue: start DMA of layer 0 into bufA
  stage_async(cs, bufA, wv);

#pragma unroll 1
  for (int i = 0; i < DEPTH; ++i) {
    const float2* cur = (i & 1) ? bufB : bufA;
    float2* nxt = (i & 1) ? bufA : bufB;

    __syncthreads();                       // nxt fully consumed (prev layer)
    // issue next layer's DMA (wrap at i=7: dummy, never read)
    stage_async(cs + ((i + 1) & 7) * 10240, nxt, wv);
    asm volatile("s_waitcnt vmcnt(5)" ::: "memory");  // cur's 5 DMAs done
    __syncthreads();                       // all waves' cur DMAs landed

    CSTEPL(0);
    CSTEPL(1);
    CSTEPL(2);
    CSTEPL(3);
    LPAIR(0, 32, 16);
    LPAIR(1, 8, 4);
    LPAIR(2, 2, 1);

    if (i != DEPTH - 1) {
      const float4* qL = qt + i * (NQ * HALF);
#pragma unroll
      for (int r = 8; r < 16; ++r) {
        int w = ((r - 8) << 6) | lane;
        s0[r - 8] += qspline(s0[r], qL, w);
      }
    }
  }

  float* op = out + (long)row * NIN;
#pragma unroll
  for (int r = 0; r < 13; ++r) {
    int w = r * 64 + lane;
    if (w < NIN) op[w] = s0[r];
  }
}

extern "C" void kernel_launch(void* const* d_in, const int* in_sizes, int n_in,
                              void* d_out, int out_size, void* d_ws, size_t ws_size,
                              hipStream_t stream) {
  const float* X  = (const float*)d_in[0];
  const float* bp = (const float*)d_in[1];   // [8,512,10]
  const float* sc = (const float*)d_in[2];   // [7,512,20]
  float* out = (float*)d_out;

  float2* cs = (float2*)d_ws;                                   // 655,360 B
  float4* qt = (float4*)((char*)d_ws + DEPTH * BDEPTH * 1024 * sizeof(float2)); // 1,032,192 B

  int prep_threads = DEPTH * BDEPTH * 1024 + (DEPTH - 1) * NQ * HALF; // 146,432
  prep_kernel<<<(prep_threads + 255) / 256, 256, 0, stream>>>(bp, sc, cs, qt);
  fwd_kernel<<<BATCH / 16, 1024, 0, stream>>>(X, cs, qt, out);
}

// Round 16
// 70.061 us; speedup vs baseline: 1.0070x; 1.0070x over previous
//
#include <hip/hip_runtime.h>

#define NIN 784
#define WIDTH 1024
#define HALF 512
#define DEPTH 8
#define BDEPTH 10
#define BATCH 4096
#define SPLINE_DIM 20
#define NQ 18   // knot intervals [t_m, t_m+1), m = 2..19

// Clamped knot vector T[23]: [-8]*3, +-2^k/32 ladder, 0, [8]*3
__device__ float d_T[23] = {
  -8.f, -8.f, -8.f, -4.f, -2.f, -1.f, -0.5f, -0.25f, -0.125f, -0.0625f,
  -0.03125f, 0.f, 0.03125f, 0.0625f, 0.125f, 0.25f, 0.5f, 1.f, 2.f, 4.f,
  8.f, 8.f, 8.f };

// ---------------------------------------------------------------------------
// Prep kernel (IDENTICAL to validated R14/R15). cs layout per layer (10240 f2):
//   d in 0..3 : [d*1024 + slot] = (c_d, s_d)
//   pairs p=0..2 (d=4+2p, d+1): [4096 + p*2048 + slot*2 + {0,1}]
//   -> one ds_read_b128 per slot feeds two consecutive steps.
// qt quadratic spline unchanged (validated R3+).
// ---------------------------------------------------------------------------
__global__ void prep_kernel(const float* __restrict__ bp,
                            const float* __restrict__ sc,
                            float2* __restrict__ cs,
                            float4* __restrict__ qt) {
  int gid = blockIdx.x * 256 + threadIdx.x;
  if (gid < DEPTH * BDEPTH * 1024) {
    int slot = gid & 1023;
    int d = (gid >> 10) % BDEPTH;
    int i = gid / (BDEPTH * 1024);
    int n = 0;
#pragma unroll
    for (int b = 0; b < 10; ++b) {
      int src = b - d; if (src < 0) src += 10;
      n |= ((slot >> src) & 1) << b;
    }
    int pj = n & 511;
    float theta = bp[(i * HALF + pj) * BDEPTH + d];
    float c = cosf(theta), s = sinf(theta);
    float2 val = make_float2(c, (n & 512) ? -s : s);
    int off;
    if (d < 4) off = i * 10240 + d * 1024 + slot;
    else {
      int p = (d - 4) >> 1, sub = (d - 4) & 1;
      off = i * 10240 + 4096 + p * 2048 + slot * 2 + sub;
    }
    cs[off] = val;
  }
  int gid2 = gid - DEPTH * BDEPTH * 1024;
  if (gid2 >= 0 && gid2 < (DEPTH - 1) * NQ * HALF) {
    int w = gid2 & 511;
    int mi = (gid2 >> 9) % NQ;
    int i = gid2 / (NQ * HALF);
    int m = mi + 2;
    const float* cf = sc + (i * HALF + w) * SPLINE_DIM;
    double c0 = cf[mi], c1 = cf[mi + 1], c2 = cf[mi + 2];
    double tm1 = d_T[m - 1], tm = d_T[m], tp1 = d_T[m + 1], tp2 = d_T[m + 2];
    double h = tp1 - tm;
    double us[3] = { 0.0, 0.5 * h, 0.75 * h };
    double y[3];
#pragma unroll
    for (int k = 0; k < 3; ++k) {
      double x = tm + us[k];
      double left1 = x - tm, right1 = tp1 - x, left2 = x - tm1, right2 = tp2 - x;
      double inv1 = 1.0 / (tp1 - tm);
      double N0 = right1 * inv1, N1 = left1 * inv1;
      double temp0 = N0 / (tp1 - tm1);
      double B0 = right1 * temp0;
      double saved = left2 * temp0;
      double temp1 = N1 / (tp2 - tm);
      double B1 = right2 * temp1 + saved;
      double B2 = left1 * temp1;
      y[k] = c0 * B0 + c1 * B1 + c2 * B2;
    }
    double d1 = y[1] - y[0], d2 = y[2] - y[0];
    double u1 = us[1], u2 = us[2];
    double det = u1 * u2 * (u2 - u1);
    double Bq = (d1 * u2 * u2 - d2 * u1 * u1) / det;
    double Cq = (d2 * u1 - d1 * u2) / det;
    qt[gid2] = make_float4((float)y[0], (float)Bq, (float)Cq, (float)tm);
  }
}

// ---------------------------------------------------------------------------
// Compile-time lane shuffles (validated): DPP xor1/2, ds_swizzle 4/8/16,
// bpermute for 32.
// ---------------------------------------------------------------------------
template <int M>
__device__ __forceinline__ float shfx(float x) {
  if constexpr (M == 1)
    return __int_as_float(__builtin_amdgcn_mov_dpp(__float_as_int(x), 0xB1, 0xF, 0xF, true));
  else if constexpr (M == 2)
    return __int_as_float(__builtin_amdgcn_mov_dpp(__float_as_int(x), 0x4E, 0xF, 0xF, true));
  else if constexpr (M == 4)
    return __int_as_float(__builtin_amdgcn_ds_swizzle(__float_as_int(x), 0x101F));
  else if constexpr (M == 8)
    return __int_as_float(__builtin_amdgcn_ds_swizzle(__float_as_int(x), 0x201F));
  else if constexpr (M == 16)
    return __int_as_float(__builtin_amdgcn_ds_swizzle(__float_as_int(x), 0x401F));
  else
    return __shfl_xor(x, 32, 64);
}

// Quadratic spline activation (validated R3+).
__device__ __forceinline__ float qspline(float x, const float4* __restrict__ qL, int w) {
  x = fminf(fmaxf(x, -8.0f), 7.9999990f);
  float ax = fabsf(x);
  unsigned bits = __float_as_uint(ax);
  int e = (int)(bits >> 23) - 127;
  int ce = e + ((bits & 0x7fffffu) ? 1 : 0);
  int m = (x > 0.f) ? (17 + e) : (5 - ce);
  m = (ax < 0.03125f) ? ((x < 0.f) ? 10 : 11) : m;
  float4 qc = qL[(m - 2) * HALF + w];
  float u = x - qc.w;
  return fmaf(u, fmaf(u, qc.z, qc.y), qc.x);
}

typedef __attribute__((address_space(3))) unsigned int lds_u32;
typedef __attribute__((address_space(1))) const unsigned int glb_u32;

// Async-stage one full layer (80 KB) into LDS buffer `dst` via global_load_lds
// (16B/lane DMA). 80 wave-segments of 1 KB; wave wv (0..15) takes segs
// {k*16+wv}, k=0..4 -> 5 DMAs/wave; wait with counted vmcnt(5) one layer later.
__device__ __forceinline__ void stage_async(const float2* __restrict__ src,
                                            float2* dst, int wv) {
#pragma unroll
  for (int k = 0; k < 5; ++k) {
    int seg = k * 16 + wv;
    const char* g = (const char*)src + seg * 1024 + (threadIdx.x & 63) * 16;
    char* l = (char*)dst + seg * 1024;
    __builtin_amdgcn_global_load_lds((glb_u32*)g, (lds_u32*)l, 16, 0, 0);
  }
}

// butterfly step dd<4: partner = reg ^ (8>>dd), one row
#define CSTEPL(dd) do {                                                       \
    const int _mr = 8 >> (dd);                                                \
    _Pragma("unroll") for (int r = 0; r < 16; ++r)                            \
      if ((r & _mr) == 0) {                                                   \
        float2 v = cur[(dd) * 1024 + r * 64 + lane];                          \
        float a0 = s0[r], b0 = s0[r + _mr];                                   \
        s0[r]       = fmaf(a0, v.x, b0 * v.y);                                \
        s0[r + _mr] = fmaf(b0, v.x, -(a0 * v.y));                             \
      }                                                                       \
  } while (0)

// paired lane-steps: one b128 feeds steps (mask M1) then (mask M2)
#define LPAIR(p, M1, M2) do {                                                 \
    const float4* _pp = (const float4*)(cur + 4096 + (p) * 2048);             \
    _Pragma("unroll") for (int r = 0; r < 16; ++r) {                          \
      float4 v = _pp[r * 64 + lane];                                          \
      float q1 = shfx<M1>(s0[r]);                                             \
      s0[r] = fmaf(s0[r], v.x, q1 * v.y);                                     \
      float q2 = shfx<M2>(s0[r]);                                             \
      s0[r] = fmaf(s0[r], v.z, q2 * v.w);                                     \
    }                                                                         \
  } while (0)

// ---------------------------------------------------------------------------
// Main kernel (structure IDENTICAL to R15; one change): explicit occupancy
// contract via amdgpu_waves_per_eu(4,4). R15's __launch_bounds__(1024,1) let
// hipcc's heuristic target 8 waves/EU (64 VGPRs) -- unreachable anyway with
// 160 KB LDS (1 block/CU = 4 waves/EU) -- so it spilled ~4 regs to scratch
// (WRITE_SIZE 12.5->16.6 MB). Pinning waves/EU to exactly 4 gives the
// allocator the true budget (512/4 = 128 VGPRs): same TLP, no spill.
// ---------------------------------------------------------------------------
__global__
__attribute__((amdgpu_flat_work_group_size(1024, 1024), amdgpu_waves_per_eu(4, 4)))
void fwd_kernel(
    const float* __restrict__ X, const float2* __restrict__ cs,
    const float4* __restrict__ qt, float* __restrict__ out) {
  __shared__ float2 bufA[10240];   // 80 KB
  __shared__ float2 bufB[10240];   // 80 KB
  int tid = threadIdx.x;
  int lane = tid & 63;
  int wv = tid >> 6;                       // 0..15
  int row = blockIdx.x * 16 + wv;

  const float* xp = X + (long)row * NIN;
  float s0[16];
#pragma unroll
  for (int r = 0; r < 16; ++r) {
    int w = r * 64 + lane;
    s0[r] = (w < NIN) ? xp[w] : 0.f;
  }

  // prologue: start DMA of layer 0 into bufA
  stage_async(cs, bufA, wv);

#pragma unroll 1
  for (int i = 0; i < DEPTH; ++i) {
    const float2* cur = (i & 1) ? bufB : bufA;
    float2* nxt = (i & 1) ? bufA : bufB;

    __syncthreads();                       // nxt fully consumed (prev layer)
    // issue next layer's DMA (wrap at i=7: dummy, never read; keeps vmcnt uniform)
    stage_async(cs + ((i + 1) & 7) * 10240, nxt, wv);
    asm volatile("s_waitcnt vmcnt(5)" ::: "memory");  // cur's 5 DMAs done
    __syncthreads();                       // all waves' cur DMAs landed

    CSTEPL(0);
    CSTEPL(1);
    CSTEPL(2);
    CSTEPL(3);
    LPAIR(0, 32, 16);
    LPAIR(1, 8, 4);
    LPAIR(2, 2, 1);

    if (i != DEPTH - 1) {
      const float4* qL = qt + i * (NQ * HALF);
#pragma unroll
      for (int r = 8; r < 16; ++r) {
        int w = ((r - 8) << 6) | lane;
        s0[r - 8] += qspline(s0[r], qL, w);
      }
    }
  }

  float* op = out + (long)row * NIN;
#pragma unroll
  for (int r = 0; r < 13; ++r) {
    int w = r * 64 + lane;
    if (w < NIN) op[w] = s0[r];
  }
}

extern "C" void kernel_launch(void* const* d_in, const int* in_sizes, int n_in,
                              void* d_out, int out_size, void* d_ws, size_t ws_size,
                              hipStream_t stream) {
  const float* X  = (const float*)d_in[0];
  const float* bp = (const float*)d_in[1];   // [8,512,10]
  const float* sc = (const float*)d_in[2];   // [7,512,20]
  float* out = (float*)d_out;

  float2* cs = (float2*)d_ws;                                   // 655,360 B
  float4* qt = (float4*)((char*)d_ws + DEPTH * BDEPTH * 1024 * sizeof(float2)); // 1,032,192 B

  int prep_threads = DEPTH * BDEPTH * 1024 + (DEPTH - 1) * NQ * HALF; // 146,432
  prep_kernel<<<(prep_threads + 255) / 256, 256, 0, stream>>>(bp, sc, cs, qt);
  fwd_kernel<<<BATCH / 16, 1024, 0, stream>>>(X, cs, qt, out);
}

// Round 17
// 61.810 us; speedup vs baseline: 1.1414x; 1.1335x over previous
//
#include <hip/hip_runtime.h>

#define NIN 784
#define WIDTH 1024
#define HALF 512
#define DEPTH 8
#define BDEPTH 10
#define BATCH 4096
#define SPLINE_DIM 20
#define NQ 18   // knot intervals [t_m, t_m+1), m = 2..19
#define LSTRIDE 8192   // float2 per layer table (64 KB)

typedef __attribute__((ext_vector_type(2))) float f32x2;

// Clamped knot vector T[23]: [-8]*3, +-2^k/32 ladder, 0, [8]*3
__device__ float d_T[23] = {
  -8.f, -8.f, -8.f, -4.f, -2.f, -1.f, -0.5f, -0.25f, -0.125f, -0.0625f,
  -0.03125f, 0.f, 0.03125f, 0.0625f, 0.125f, 0.25f, 0.5f, 1.f, 2.f, 4.f,
  8.f, 8.f, 8.f };

// ---------------------------------------------------------------------------
// Prep kernel (rotation math validated R3-R16). NEW cs layout per layer
// (8192 float2 = 64 KB):
//   tbl0 [0,1024):    float4[512]  steps 0,1 packed: entry (q,lane):
//                     .xy = step0 coeff at zero-slot r=q (pair q,q+8)
//                     .zw = step1 coeff at zero-slot r1 = q<4?q:q+4 (pair r1,r1+4)
//   tbl1 [1024,2048): float4[512]  steps 2,3 packed:
//                     .xy = step2 at r2 = ((q>>1)<<2)|(q&1) (pair r2,r2+2)
//                     .zw = step3 at r3 = 2q (pair r3,r3+1)
//   LP p∈0..2 [2048+p*2048, ...): float4[1024] steps 4+2p,5+2p per slot
// qt quadratic spline unchanged (validated R3+).
// ---------------------------------------------------------------------------
__global__ void prep_kernel(const float* __restrict__ bp,
                            const float* __restrict__ sc,
                            float2* __restrict__ cs,
                            float4* __restrict__ qt) {
  int gid = blockIdx.x * 256 + threadIdx.x;
  if (gid < DEPTH * BDEPTH * 1024) {
    int slot = gid & 1023;
    int d = (gid >> 10) % BDEPTH;
    int i = gid / (BDEPTH * 1024);
    int n = 0;
#pragma unroll
    for (int b = 0; b < 10; ++b) {
      int src = b - d; if (src < 0) src += 10;
      n |= ((slot >> src) & 1) << b;
    }
    int pj = n & 511;
    float theta = bp[(i * HALF + pj) * BDEPTH + d];
    float c = cosf(theta), s = sinf(theta);
    float2 val = make_float2(c, (n & 512) ? -s : s);
    long base = (long)i * LSTRIDE;
    if (d < 4) {
      int r = slot >> 6, lane = slot & 63;
      int mr = 8 >> d;
      if ((r & mr) == 0) {                 // zero-slot: this one is stored
        int q;
        if (d == 0)      q = r;                          // r in 0..7
        else if (d == 1) q = (r & 3) | ((r >> 3) << 2);  // {0..3,8..11} -> 0..7
        else if (d == 2) q = ((r >> 2) << 1) | (r & 1);  // {0,1,4,5,8,9,12,13}
        else             q = r >> 1;                     // evens -> 0..7
        int tbl = d >> 1, sub = d & 1;
        cs[base + tbl * 1024 + (q * 64 + lane) * 2 + sub] = val;
      }
    } else {
      int p = (d - 4) >> 1, sub = (d - 4) & 1;
      cs[base + 2048 + p * 2048 + slot * 2 + sub] = val;
    }
  }
  int gid2 = gid - DEPTH * BDEPTH * 1024;
  if (gid2 >= 0 && gid2 < (DEPTH - 1) * NQ * HALF) {
    int w = gid2 & 511;
    int mi = (gid2 >> 9) % NQ;
    int i = gid2 / (NQ * HALF);
    int m = mi + 2;
    const float* cf = sc + (i * HALF + w) * SPLINE_DIM;
    double c0 = cf[mi], c1 = cf[mi + 1], c2 = cf[mi + 2];
    double tm1 = d_T[m - 1], tm = d_T[m], tp1 = d_T[m + 1], tp2 = d_T[m + 2];
    double h = tp1 - tm;
    double us[3] = { 0.0, 0.5 * h, 0.75 * h };
    double y[3];
#pragma unroll
    for (int k = 0; k < 3; ++k) {
      double x = tm + us[k];
      double left1 = x - tm, right1 = tp1 - x, left2 = x - tm1, right2 = tp2 - x;
      double inv1 = 1.0 / (tp1 - tm);
      double N0 = right1 * inv1, N1 = left1 * inv1;
      double temp0 = N0 / (tp1 - tm1);
      double B0 = right1 * temp0;
      double saved = left2 * temp0;
      double temp1 = N1 / (tp2 - tm);
      double B1 = right2 * temp1 + saved;
      double B2 = left1 * temp1;
      y[k] = c0 * B0 + c1 * B1 + c2 * B2;
    }
    double d1 = y[1] - y[0], d2 = y[2] - y[0];
    double u1 = us[1], u2 = us[2];
    double det = u1 * u2 * (u2 - u1);
    double Bq = (d1 * u2 * u2 - d2 * u1 * u1) / det;
    double Cq = (d2 * u1 - d1 * u2) / det;
    qt[gid2] = make_float4((float)y[0], (float)Bq, (float)Cq, (float)tm);
  }
}

// ---------------------------------------------------------------------------
// Lane shuffles, minimizing DS-pipe ops:
//   M=1,2  : DPP quad_perm           (VALU)
//   M=4    : ds_swizzle              (DS -- only remaining DS shuffle)
//   M=8    : DPP row_ror:8 (i+8 mod 16 == i^8)            (VALU)
//   M=16   : v_permlane16_swap(v,v) + cndmask on lane&16  (VALU)
//   M=32   : v_permlane32_swap(v,v) + cndmask on lane&32  (VALU)
// ---------------------------------------------------------------------------
template <int M>
__device__ __forceinline__ float shfx(float x, int lane) {
  if constexpr (M == 1)
    return __int_as_float(__builtin_amdgcn_mov_dpp(__float_as_int(x), 0xB1, 0xF, 0xF, true));
  else if constexpr (M == 2)
    return __int_as_float(__builtin_amdgcn_mov_dpp(__float_as_int(x), 0x4E, 0xF, 0xF, true));
  else if constexpr (M == 4)
    return __int_as_float(__builtin_amdgcn_ds_swizzle(__float_as_int(x), 0x101F));
  else if constexpr (M == 8)
    return __int_as_float(__builtin_amdgcn_mov_dpp(__float_as_int(x), 0x128, 0xF, 0xF, true));
  else if constexpr (M == 16) {
#if __has_builtin(__builtin_amdgcn_permlane16_swap)
    auto pr = __builtin_amdgcn_permlane16_swap(__float_as_uint(x), __float_as_uint(x), false, false);
    return __uint_as_float((lane & 16) ? pr[0] : pr[1]);
#else
    return __int_as_float(__builtin_amdgcn_ds_swizzle(__float_as_int(x), 0x401F));
#endif
  } else {
#if __has_builtin(__builtin_amdgcn_permlane32_swap)
    auto pr = __builtin_amdgcn_permlane32_swap(__float_as_uint(x), __float_as_uint(x), false, false);
    return __uint_as_float((lane & 32) ? pr[0] : pr[1]);
#else
    return __shfl_xor(x, 32, 64);
#endif
  }
}

// Quadratic spline activation (validated R3+).
__device__ __forceinline__ float qspline(float x, const float4* __restrict__ qL, int w) {
  x = fminf(fmaxf(x, -8.0f), 7.9999990f);
  float ax = fabsf(x);
  unsigned bits = __float_as_uint(ax);
  int e = (int)(bits >> 23) - 127;
  int ce = e + ((bits & 0x7fffffu) ? 1 : 0);
  int m = (x > 0.f) ? (17 + e) : (5 - ce);
  m = (ax < 0.03125f) ? ((x < 0.f) ? 10 : 11) : m;
  float4 qc = qL[(m - 2) * HALF + w];
  float u = x - qc.w;
  return fmaf(u, fmaf(u, qc.z, qc.y), qc.x);
}

typedef __attribute__((address_space(3))) unsigned int lds_u32;
typedef __attribute__((address_space(1))) const unsigned int glb_u32;

// Async-stage one full layer (64 KB) into LDS buffer `dst` via global_load_lds
// (16B/lane DMA). 64 wave-segments of 1 KB; wave wv (0..7) takes segs
// {k*8+wv}, k=0..7 -> 8 DMAs/wave; wait with counted vmcnt(8) one layer later.
__device__ __forceinline__ void stage_async(const float2* __restrict__ src,
                                            float2* dst, int wv) {
#pragma unroll
  for (int k = 0; k < 8; ++k) {
    int seg = k * 8 + wv;
    const char* g = (const char*)src + seg * 1024 + (threadIdx.x & 63) * 16;
    char* l = (char*)dst + seg * 1024;
    __builtin_amdgcn_global_load_lds((glb_u32*)g, (lds_u32*)l, 16, 0, 0);
  }
}

// pair rotation on packed 2-row state
#define ROT(rz, rp, cc, ss) do {                                              \
    f32x2 _a = st[rz], _b = st[rp];                                           \
    f32x2 _vc = {cc, cc}, _vs = {ss, ss};                                     \
    st[rz] = __builtin_elementwise_fma(_a, _vc, _b * _vs);                    \
    st[rp] = __builtin_elementwise_fma(_b, _vc, -(_a * _vs));                 \
  } while (0)

// paired lane-steps: one b128 feeds steps (mask M1) then (mask M2)
#define LPAIR(p, M1, M2) do {                                                 \
    const float4* _pp = (const float4*)(cur + 2048 + (p) * 2048);             \
    _Pragma("unroll") for (int r = 0; r < 16; ++r) {                          \
      float4 v = _pp[r * 64 + lane];                                          \
      f32x2 q1 = { shfx<M1>(st[r].x, lane), shfx<M1>(st[r].y, lane) };        \
      st[r] = __builtin_elementwise_fma(st[r], (f32x2){v.x, v.x},             \
                                        q1 * (f32x2){v.y, v.y});              \
      f32x2 q2 = { shfx<M2>(st[r].x, lane), shfx<M2>(st[r].y, lane) };        \
      st[r] = __builtin_elementwise_fma(st[r], (f32x2){v.z, v.z},             \
                                        q2 * (f32x2){v.w, v.w});              \
    }                                                                         \
  } while (0)

// ---------------------------------------------------------------------------
// Main kernel: 256 blocks x 512 threads (8 waves), TWO rows per wave packed
// f32x2 (R14 no-spill geometry). DS-instruction diet vs R14:
//   shuffles: masks 32,16 -> permlane*_swap (VALU); 8 -> DPP row_ror:8; only
//             mask 4 stays ds_swizzle  (128 -> 32 DS ops/wave/layer)
//   steps 0-3: two steps per ds_read_b128 (32 b64 -> 16 b128)
// Total DS/wave/layer 208 -> 96. Layer table 80->64 KB, dbuf 128 KB,
// async-staged with counted vmcnt(8), 2 barriers/layer.
// ---------------------------------------------------------------------------
__global__ __launch_bounds__(512, 1) void fwd_kernel(
    const float* __restrict__ X, const float2* __restrict__ cs,
    const float4* __restrict__ qt, float* __restrict__ out) {
  __shared__ float2 bufA[LSTRIDE];   // 64 KB
  __shared__ float2 bufB[LSTRIDE];   // 64 KB
  int tid = threadIdx.x;
  int lane = tid & 63;
  int wv = tid >> 6;                       // 0..7
  int row0 = blockIdx.x * 16 + wv * 2;

  const float* x0p = X + (long)row0 * NIN;
  const float* x1p = X + (long)(row0 + 1) * NIN;
  f32x2 st[16];
#pragma unroll
  for (int r = 0; r < 16; ++r) {
    int w = r * 64 + lane;
    bool in = (w < NIN);
    st[r] = (f32x2){ in ? x0p[w] : 0.f, in ? x1p[w] : 0.f };
  }

  // prologue: start DMA of layer 0 into bufA
  stage_async(cs, bufA, wv);

#pragma unroll 1
  for (int i = 0; i < DEPTH; ++i) {
    const float2* cur = (i & 1) ? bufB : bufA;
    float2* nxt = (i & 1) ? bufA : bufB;

    __syncthreads();                       // nxt fully consumed (prev layer)
    stage_async(cs + ((i + 1) & 7) * LSTRIDE, nxt, wv);  // next layer (i=7: dummy)
    asm volatile("s_waitcnt vmcnt(8)" ::: "memory");     // cur's 8 DMAs done
    __syncthreads();                       // all waves' cur DMAs landed

    // ---- steps 0,1 from tbl0
    {
      const float4* cp = (const float4*)cur;
      float4 V[8];
#pragma unroll
      for (int q = 0; q < 8; ++q) V[q] = cp[q * 64 + lane];
#pragma unroll
      for (int q = 0; q < 8; ++q) ROT(q, q + 8, V[q].x, V[q].y);
#pragma unroll
      for (int q = 0; q < 8; ++q) {
        const int rz = (q < 4) ? q : q + 4;
        ROT(rz, rz + 4, V[q].z, V[q].w);
      }
    }
    // ---- steps 2,3 from tbl1
    {
      const float4* cp = (const float4*)(cur + 1024);
      float4 V[8];
#pragma unroll
      for (int q = 0; q < 8; ++q) V[q] = cp[q * 64 + lane];
#pragma unroll
      for (int q = 0; q < 8; ++q) {
        const int rz = ((q >> 1) << 2) | (q & 1);
        ROT(rz, rz + 2, V[q].x, V[q].y);
      }
#pragma unroll
      for (int q = 0; q < 8; ++q) {
        const int rz = 2 * q;
        ROT(rz, rz + 1, V[q].z, V[q].w);
      }
    }
    // ---- steps 4-9
    LPAIR(0, 32, 16);
    LPAIR(1, 8, 4);
    LPAIR(2, 2, 1);

    if (i != DEPTH - 1) {
      const float4* qL = qt + i * (NQ * HALF);
#pragma unroll
      for (int r = 8; r < 16; ++r) {
        int w = ((r - 8) << 6) | lane;
        st[r - 8].x += qspline(st[r].x, qL, w);
        st[r - 8].y += qspline(st[r].y, qL, w);
      }
    }
  }

  float* o0 = out + (long)row0 * NIN;
  float* o1 = out + (long)(row0 + 1) * NIN;
#pragma unroll
  for (int r = 0; r < 13; ++r) {
    int w = r * 64 + lane;
    if (w < NIN) { o0[w] = st[r].x; o1[w] = st[r].y; }
  }
}

extern "C" void kernel_launch(void* const* d_in, const int* in_sizes, int n_in,
                              void* d_out, int out_size, void* d_ws, size_t ws_size,
                              hipStream_t stream) {
  const float* X  = (const float*)d_in[0];
  const float* bp = (const float*)d_in[1];   // [8,512,10]
  const float* sc = (const float*)d_in[2];   // [7,512,20]
  float* out = (float*)d_out;

  float2* cs = (float2*)d_ws;                                   // 524,288 B
  float4* qt = (float4*)((char*)d_ws + DEPTH * LSTRIDE * sizeof(float2)); // 1,032,192 B

  int prep_threads = DEPTH * BDEPTH * 1024 + (DEPTH - 1) * NQ * HALF; // 146,432
  prep_kernel<<<(prep_threads + 255) / 256, 256, 0, stream>>>(bp, sc, cs, qt);
  fwd_kernel<<<BATCH / 16, 512, 0, stream>>>(X, cs, qt, out);
}